// Round 4
// baseline (243.844 us; speedup 1.0000x reference)
//
#include <hip/hip_runtime.h>
#include <hip/hip_bf16.h>

// FeatureAdaption R4: MFR>1 (B-read reuse), 1-iter software-pipelined A-path,
// co-split for occupancy. conv1(256->256) -> conv2(256->72)=offsets ->
// deform conv v1 + ReLU. B=8, C=256, H=W=64, dg=4, K=9.

typedef __attribute__((ext_vector_type(8))) short bf16x8;
typedef __attribute__((ext_vector_type(4))) float f32x4;

static __device__ __forceinline__ ushort f2bf(float f) {
  __hip_bfloat16 h = __float2bfloat16(f);
  return *reinterpret_cast<ushort*>(&h);
}
static __device__ __forceinline__ float bf2f(ushort u) {
  union { uint u32; float f; } cv;
  cv.u32 = ((uint)u) << 16;
  return cv.f;
}

// ---------------- weight prep (verified R2/R3) ----------------
__global__ __launch_bounds__(256) void prep_weights(
    const float* __restrict__ w1, const float* __restrict__ w2,
    const float* __restrict__ wd,
    ushort* __restrict__ wt1b, ushort* __restrict__ wt2b,
    ushort* __restrict__ wtdb) {
  const int N1 = 256 * 2304, N2 = 128 * 2304, N3 = 256 * 2304;
  int total = N1 + N2 + N3;
  for (int i = blockIdx.x * 256 + threadIdx.x; i < total; i += gridDim.x * 256) {
    if (i < N1) {
      int co = i / 2304, r = i % 2304;
      int ti = r >> 6, cc = r & 63;
      int kk = ti >> 2, chunk = ti & 3;
      wt1b[i] = f2bf(w1[(co * 256 + chunk * 64 + cc) * 9 + kk]);
    } else if (i < N1 + N2) {
      int d = i - N1;
      int co = d / 2304, r = d % 2304;
      int ti = r >> 6, cc = r & 63;
      int kk = ti >> 2, chunk = ti & 3;
      wt2b[d] = (co < 72) ? f2bf(w2[(co * 256 + chunk * 64 + cc) * 9 + kk])
                          : (ushort)0;
    } else {
      int d = i - N1 - N2;
      int co = d / 2304, r = d % 2304;
      int ti = r >> 6, c = r & 63;
      int g = ti / 9, kk = ti - g * 9;
      wtdb[d] = f2bf(wd[(co * 256 + g * 64 + c) * 9 + kk]);
    }
  }
}

// ---------------- x -> channel-last grouped bf16 (verified R3) ----------------
__global__ __launch_bounds__(256) void transpose_x(
    const float* __restrict__ x, ushort* __restrict__ xt) {
  int id = blockIdx.x;
  int y = id & 63, bg = id >> 6;
  int c = threadIdx.x & 63, xi = threadIdx.x >> 6;
  const float* ip = x + (((size_t)bg) << 18) + ((size_t)c << 12) + y * 64;
  ushort* op = xt + (((size_t)bg) << 18) + (size_t)y * 4096 + c;
#pragma unroll
  for (int j = 0; j < 16; ++j) {
    int xx = xi * 16 + j;
    op[(size_t)xx * 64] = f2bf(ip[xx]);
  }
}

// ---------------- unified MFMA kernel v3 ----------------
// Wave = MFR*16 px  x  NFR*16 co. Block = NWAVES waves stacked in M.
// B tile (CO_TILE x 64k, pitch 144B) double-buffered via global_load_lds.
// A-path software-pipelined one iteration ahead.
template <int MODE, int MFR, int NFR, int NWAVES, int NSPLIT,
          bool RELU, bool HASBIAS, bool OUT_CHLAST, int MINW>
__global__ __launch_bounds__(NWAVES * 64, MINW) void fa_mfma3(
    const ushort* __restrict__ inT,  // [bg][4096 px][64 c] bf16
    const float* __restrict__ off,   // [B][72][64][64] f32 (MODE 1)
    const ushort* __restrict__ wB,   // [co_total][2304] bf16
    const float* __restrict__ bias,
    void* __restrict__ outp,
    int co_total, int co_write) {
  constexpr int THREADS = NWAVES * 64;
  constexpr int CO_TILE = NFR * 16;
  constexpr int MB = NWAVES * MFR * 16;
  constexpr int ROWS = MB / 64;
  constexpr int NCALLS = (CO_TILE * 144 + THREADS * 16 - 1) / (THREADS * 16);
  constexpr int BUFN = NCALLS * THREADS * 8;  // ushorts per buffer
  constexpr int NRN = (MODE == 1) ? 8 : 2;
  __shared__ __align__(16) ushort Blds[2][BUFN];

  const int nwg = 8 * (64 / ROWS) * NSPLIT;
  int id = blockIdx.x;
  int id2 = (id & 7) * (nwg >> 3) + (id >> 3);   // XCD swizzle (nwg%8==0)
  int coh = id2 % NSPLIT;
  int rg = (id2 / NSPLIT) % (64 / ROWS);
  int b = id2 / (NSPLIT * (64 / ROWS));
  int h0 = rg * ROWS;
  int co_base = coh * CO_TILE;

  int t = threadIdx.x;
  int wv = t >> 6, lane = t & 63;
  int ml = lane & 15, kc = lane >> 4;

  const char* wBb = (const char*)(wB + (size_t)co_base * 2304);

  int rb_i[NCALLS];
#pragma unroll
  for (int m = 0; m < NCALLS; ++m) {
    int dest = (m * THREADS + t) * 16;
    int co = dest / 144;
    int r = dest - co * 144;
    if (co > CO_TILE - 1) co = CO_TILE - 1;
    rb_i[m] = co * 4608 + (r >= 128 ? 0 : r);
  }

  auto stage = [&](int ti, int bufsel) {
#pragma unroll
    for (int m = 0; m < NCALLS; ++m) {
      const void* src = (const void*)(wBb + ((size_t)rb_i[m] + ti * 128));
      ushort* dst = &Blds[bufsel][(m * THREADS + t) * 8];
      __builtin_amdgcn_global_load_lds(
          (const __attribute__((address_space(1))) void*)src,
          (__attribute__((address_space(3))) void*)dst, 16, 0, 0);
    }
  };

  int prow[MFR], pcol[MFR];
#pragma unroll
  for (int mf = 0; mf < MFR; ++mf) {
    int pxg = wv * MFR * 16 + mf * 16 + ml;
    prow[mf] = h0 + (pxg >> 6);
    pcol[mf] = pxg & 63;
  }

  const bf16x8 bz = {0, 0, 0, 0, 0, 0, 0, 0};
  bf16x8 aCur[MFR][2];
  bf16x8 rN[MFR][NRN];
  float wsv[MFR][4];
  float2 offA[MFR];

  // ---- MODE 0: direct conv A-path ----
  auto issueA0 = [&](int tn) {
    int kk = tn >> 2, chunk = tn & 3;
    int ky = kk / 3, kx = kk - ky * 3;
#pragma unroll
    for (int mf = 0; mf < MFR; ++mf) {
      int gy = prow[mf] + ky - 1, gx = pcol[mf] + kx - 1;
      bool inb = (gy >= 0) & (gy < 64) & (gx >= 0) & (gx < 64);
      const ushort* p =
          inT + ((((size_t)(b * 4 + chunk) << 12) + gy * 64 + gx) << 6) + kc * 8;
      rN[mf][0] = bz;
      rN[mf][1] = bz;
      if (inb) {
        rN[mf][0] = *(const bf16x8*)p;
        rN[mf][1] = *(const bf16x8*)(p + 32);
      }
    }
  };
  auto finishA0 = [&]() {
#pragma unroll
    for (int mf = 0; mf < MFR; ++mf) {
      aCur[mf][0] = rN[mf][0];
      aCur[mf][1] = rN[mf][1];
    }
  };

  // ---- MODE 1: deform A-path ----
  auto loadOff = [&](int tn) {
    int g = tn / 9, kk = tn - 9 * (tn / 9);
    int ch = g * 18 + kk * 2;
#pragma unroll
    for (int mf = 0; mf < MFR; ++mf) {
      const float* offp =
          off + (((size_t)b * 72 + ch) << 12) + prow[mf] * 64 + pcol[mf];
      offA[mf].x = offp[0];
      offA[mf].y = offp[4096];
    }
  };
  auto issueA1 = [&](int tn) {
    int g = tn / 9, kk = tn - 9 * (tn / 9);
    int ky = kk / 3, kx = kk - ky * 3;
    const ushort* base = inT + (((size_t)(b * 4 + g)) << 18) + kc * 8;
#pragma unroll
    for (int mf = 0; mf < MFR; ++mf) {
      float py = (float)(prow[mf] + ky - 1) + offA[mf].x;
      float pxf = (float)(pcol[mf] + kx - 1) + offA[mf].y;
      float y0f = floorf(py), x0f = floorf(pxf);
      float wy1 = py - y0f, wx1 = pxf - x0f;
      float wy0 = 1.f - wy1, wx0 = 1.f - wx1;
      int y0 = (int)y0f, x0i = (int)x0f;
      int y1 = y0 + 1, x1i = x0i + 1;
      bool vy0 = (y0 >= 0) & (y0 < 64);
      bool vy1 = (y1 >= 0) & (y1 < 64);
      bool vx0 = (x0i >= 0) & (x0i < 64);
      bool vx1 = (x1i >= 0) & (x1i < 64);
      wsv[mf][0] = (vy0 & vx0) ? wy0 * wx0 : 0.f;
      wsv[mf][1] = (vy0 & vx1) ? wy0 * wx1 : 0.f;
      wsv[mf][2] = (vy1 & vx0) ? wy1 * wx0 : 0.f;
      wsv[mf][3] = (vy1 & vx1) ? wy1 * wx1 : 0.f;
      int yc0 = min(max(y0, 0), 63), yc1 = min(max(y1, 0), 63);
      int xc0 = min(max(x0i, 0), 63), xc1 = min(max(x1i, 0), 63);
      const ushort* p00 = base + ((yc0 * 64 + xc0) << 6);
      const ushort* p01 = base + ((yc0 * 64 + xc1) << 6);
      const ushort* p10 = base + ((yc1 * 64 + xc0) << 6);
      const ushort* p11 = base + ((yc1 * 64 + xc1) << 6);
      rN[mf][0] = *(const bf16x8*)p00;
      rN[mf][1] = *(const bf16x8*)(p00 + 32);
      rN[mf][2] = *(const bf16x8*)p01;
      rN[mf][3] = *(const bf16x8*)(p01 + 32);
      rN[mf][4] = *(const bf16x8*)p10;
      rN[mf][5] = *(const bf16x8*)(p10 + 32);
      rN[mf][6] = *(const bf16x8*)p11;
      rN[mf][7] = *(const bf16x8*)(p11 + 32);
    }
  };
  auto finishA1 = [&]() {
#pragma unroll
    for (int mf = 0; mf < MFR; ++mf) {
      float w00 = wsv[mf][0], w01 = wsv[mf][1];
      float w10 = wsv[mf][2], w11 = wsv[mf][3];
#pragma unroll
      for (int ks = 0; ks < 2; ++ks) {
        bf16x8 q00 = rN[mf][0 + ks], q01 = rN[mf][2 + ks];
        bf16x8 q10 = rN[mf][4 + ks], q11 = rN[mf][6 + ks];
        bf16x8 av;
#pragma unroll
        for (int jj = 0; jj < 4; ++jj) {
          float v0 = w00 * bf2f((ushort)q00[2 * jj]) + w01 * bf2f((ushort)q01[2 * jj]) +
                     w10 * bf2f((ushort)q10[2 * jj]) + w11 * bf2f((ushort)q11[2 * jj]);
          float v1 = w00 * bf2f((ushort)q00[2 * jj + 1]) + w01 * bf2f((ushort)q01[2 * jj + 1]) +
                     w10 * bf2f((ushort)q10[2 * jj + 1]) + w11 * bf2f((ushort)q11[2 * jj + 1]);
          av[2 * jj] = (short)f2bf(v0);
          av[2 * jj + 1] = (short)f2bf(v1);
        }
        aCur[mf][ks] = av;
      }
    }
  };

  f32x4 acc[MFR][NFR];
#pragma unroll
  for (int i = 0; i < MFR; ++i)
#pragma unroll
    for (int j = 0; j < NFR; ++j) acc[i][j] = (f32x4){0.f, 0.f, 0.f, 0.f};

  // prologue: A(0) built, B(0) staged
  if (MODE == 1) {
    loadOff(0);
    issueA1(0);
    loadOff(1);
    finishA1();
  } else {
    issueA0(0);
    finishA0();
  }
  stage(0, 0);
  __syncthreads();

  for (int ti = 0; ti < 36; ++ti) {
    int cur = ti & 1;
    if (ti < 35) {
      stage(ti + 1, cur ^ 1);
      if (MODE == 1) issueA1(ti + 1); else issueA0(ti + 1);
    }
    if (MODE == 1 && ti < 34) loadOff(ti + 2);

#pragma unroll
    for (int ks = 0; ks < 2; ++ks) {
      bf16x8 bq[NFR];
#pragma unroll
      for (int nf = 0; nf < NFR; ++nf)
        bq[nf] = *(const bf16x8*)&Blds[cur][(nf * 16 + ml) * 72 + ks * 32 + kc * 8];
#pragma unroll
      for (int mf = 0; mf < MFR; ++mf)
#pragma unroll
        for (int nf = 0; nf < NFR; ++nf)
          acc[mf][nf] = __builtin_amdgcn_mfma_f32_16x16x32_bf16(
              aCur[mf][ks], bq[nf], acc[mf][nf], 0, 0, 0);
    }

    if (ti < 35) { if (MODE == 1) finishA1(); else finishA0(); }
    __syncthreads();
  }

  // epilogue: D col = lane&15 (co), row = (lane>>4)*4 + ri (px)
  int rq = lane >> 4;
#pragma unroll
  for (int nf = 0; nf < NFR; ++nf) {
    int cog = co_base + nf * 16 + ml;
    if (cog < co_write) {
      float bv = HASBIAS ? bias[cog] : 0.f;
#pragma unroll
      for (int mf = 0; mf < MFR; ++mf) {
#pragma unroll
        for (int ri = 0; ri < 4; ++ri) {
          int pxe = wv * MFR * 16 + mf * 16 + rq * 4 + ri;
          int row = h0 + (pxe >> 6), col = pxe & 63;
          float v = acc[mf][nf][ri] + bv;
          if (RELU) v = fmaxf(v, 0.f);
          if (OUT_CHLAST) {
            int g_out = cog >> 6, ci = cog & 63;
            ((ushort*)outp)[((((size_t)(b * 4 + g_out) << 12) + row * 64 + col) << 6) + ci] =
                f2bf(v);
          } else {
            ((float*)outp)[(((size_t)b * co_total + cog) << 12) + row * 64 + col] = v;
          }
        }
      }
    }
  }
}

extern "C" void kernel_launch(void* const* d_in, const int* in_sizes, int n_in,
                              void* d_out, int out_size, void* d_ws, size_t ws_size,
                              hipStream_t stream) {
  const float* x  = (const float*)d_in[0];
  const float* w1 = (const float*)d_in[1];
  const float* b1 = (const float*)d_in[2];
  const float* w2 = (const float*)d_in[3];
  const float* b2 = (const float*)d_in[4];
  const float* wd = (const float*)d_in[5];

  char* wsb = (char*)d_ws;
  float*  off_buf = (float*)wsb;                  //  9,437,184 B
  ushort* xt      = (ushort*)(wsb + 9437184);     // 16,777,216 B
  ushort* wt1b    = (ushort*)(wsb + 26214400);    //  1,179,648 B
  ushort* wt2b    = (ushort*)(wsb + 27394048);    //    589,824 B
  ushort* wtdb    = (ushort*)(wsb + 27983872);    //  1,179,648 B -> 27.8 MB

  prep_weights<<<2048, 256, 0, stream>>>(w1, w2, wd, wt1b, wt2b, wtdb);
  transpose_x<<<2048, 256, 0, stream>>>(x, xt);

  // conv1: MFR=4, NFR=8, 2 waves, co-split 2 -> grid 8*32*2=512, 128 thr
  fa_mfma3<0, 4, 8, 2, 2, false, true, true, 1>
      <<<512, 128, 0, stream>>>(xt, nullptr, wt1b, b1, d_out, 256, 256);

  // conv2: MFR=2, NFR=5, 2 waves, no split -> grid 8*64=512, 128 thr
  fa_mfma3<0, 2, 5, 2, 1, false, true, false, 2>
      <<<512, 128, 0, stream>>>((const ushort*)d_out, nullptr, wt2b, b2,
                                off_buf, 72, 72);

  // deform: MFR=2, NFR=8, 4 waves, co-split 2 -> grid 8*32*2=512, 256 thr
  fa_mfma3<1, 2, 8, 4, 2, true, false, false, 2>
      <<<512, 256, 0, stream>>>(xt, off_buf, wtdb, nullptr, d_out, 256, 256);
}

// Round 5
// 204.306 us; speedup vs baseline: 1.1935x; 1.1935x over previous
//
#include <hip/hip_runtime.h>
#include <hip/hip_bf16.h>

// FeatureAdaption R5: MFR=2/NFR=16 waves (no co-split), XOR-swizzled B tiles
// (pre-swizzled source + linear global_load_lds), pipelined A-path.
// conv1(256->256) -> conv2(256->72)=offsets -> deform conv v1 + ReLU.
// B=8, C=256, H=W=64, dg=4, K=9.

typedef __attribute__((ext_vector_type(8))) short bf16x8;
typedef __attribute__((ext_vector_type(4))) float f32x4;

static __device__ __forceinline__ ushort f2bf(float f) {
  __hip_bfloat16 h = __float2bfloat16(f);
  return *reinterpret_cast<ushort*>(&h);
}
static __device__ __forceinline__ float bf2f(ushort u) {
  union { uint u32; float f; } cv;
  cv.u32 = ((uint)u) << 16;
  return cv.f;
}

// ---------------- weight prep: swizzled tiles ----------------
// Output layout: [ti][co][p][e]  (p = 16B slot 0..7, e = bf16 0..7)
// stored value = orig[co][ k = ti*64 + (p ^ (co&7))*8 + e ]
// conv K-order: ti = kk*4 + chunk, channel ci = chunk*64 + cc (cc = in-tile)
// deform:       ti = g*9 + kk,     channel c  = in-tile
__global__ __launch_bounds__(256) void prep_weights(
    const float* __restrict__ w1, const float* __restrict__ w2,
    const float* __restrict__ wd,
    ushort* __restrict__ wt1s, ushort* __restrict__ wt2s,
    ushort* __restrict__ wtds) {
  const int N1 = 36 * 256 * 64;   // 589824
  const int N2 = 36 * 80 * 64;    // 184320
  const int N3 = 36 * 256 * 64;   // 589824
  int total = N1 + N2 + N3;
  for (int i = blockIdx.x * 256 + threadIdx.x; i < total; i += gridDim.x * 256) {
    if (i < N1) {
      int e = i & 7, p = (i >> 3) & 7, co = (i >> 6) & 255, ti = i >> 14;
      int cc = ((p ^ (co & 7)) << 3) + e;
      int kk = ti >> 2, chunk = ti & 3;
      wt1s[i] = f2bf(w1[(co * 256 + chunk * 64 + cc) * 9 + kk]);
    } else if (i < N1 + N2) {
      int d = i - N1;
      int e = d & 7, p = (d >> 3) & 7;
      int r = d >> 6;
      int co = r % 80, ti = r / 80;
      int cc = ((p ^ (co & 7)) << 3) + e;
      int kk = ti >> 2, chunk = ti & 3;
      wt2s[d] = (co < 72) ? f2bf(w2[(co * 256 + chunk * 64 + cc) * 9 + kk])
                          : (ushort)0;
    } else {
      int d = i - N1 - N2;
      int e = d & 7, p = (d >> 3) & 7, co = (d >> 6) & 255, ti = d >> 14;
      int c = ((p ^ (co & 7)) << 3) + e;
      int g = ti / 9, kk = ti - g * 9;
      wtds[d] = f2bf(wd[(co * 256 + g * 64 + c) * 9 + kk]);
    }
  }
}

// ---------------- x -> channel-last grouped bf16 (verified R3/R4) ----------------
__global__ __launch_bounds__(256) void transpose_x(
    const float* __restrict__ x, ushort* __restrict__ xt) {
  int id = blockIdx.x;
  int y = id & 63, bg = id >> 6;
  int c = threadIdx.x & 63, xi = threadIdx.x >> 6;
  const float* ip = x + (((size_t)bg) << 18) + ((size_t)c << 12) + y * 64;
  ushort* op = xt + (((size_t)bg) << 18) + (size_t)y * 4096 + c;
#pragma unroll
  for (int j = 0; j < 16; ++j) {
    int xx = xi * 16 + j;
    op[(size_t)xx * 64] = f2bf(ip[xx]);
  }
}

// ---------------- unified MFMA kernel v4 ----------------
// Block = (b,h) row [XCD swizzled], 2 waves; wave w owns px [w*32, w*32+32)
// (MFR=2 frags), all CO_TILE=NFR*16 outputs (no A-duplication).
// B tile [co][64k] XOR-swizzled in LDS (conflict-free b128), double-buffered,
// staged linearly via global_load_lds from pre-swizzled source tiles.
// A-path software-pipelined one iteration ahead (offsets two ahead).
template <int MODE, int MFR, int NFR, bool RELU, bool HASBIAS, bool OUT_CHLAST>
__global__ __launch_bounds__(128, 1) void fa_mfma4(
    const ushort* __restrict__ inT,  // [bg][4096 px][64 c] bf16
    const float* __restrict__ off,   // [B][72][64][64] f32 (MODE 1)
    const char* __restrict__ wBs,    // swizzled tiles [36][CO_TILE*128 bytes]
    const float* __restrict__ bias,
    void* __restrict__ outp,
    int co_total, int co_write) {
  constexpr int CO_TILE = NFR * 16;
  constexpr int TILE_B = CO_TILE * 128;          // bytes per K-tile
  constexpr int NCALLS = TILE_B / (128 * 16);
  constexpr int NRN = (MODE == 1) ? 8 : 2;
  __shared__ __align__(16) ushort Blds[2][CO_TILE * 64];

  int id = blockIdx.x;
  int id2 = (id & 7) * 64 + (id >> 3);           // XCD swizzle (512 = 8*64)
  int b = id2 >> 6, h = id2 & 63;
  int t = threadIdx.x;
  int wv = t >> 6, lane = t & 63;
  int ml = lane & 15, kc = lane >> 4;
  int ml7 = ml & 7;

  auto stage = [&](int ti, int bufsel) {
    const char* src0 = wBs + (size_t)ti * TILE_B + t * 16;
    ushort* dst0 = &Blds[bufsel][t * 8];
#pragma unroll
    for (int m = 0; m < NCALLS; ++m) {
      __builtin_amdgcn_global_load_lds(
          (const __attribute__((address_space(1))) void*)(src0 + m * 2048),
          (__attribute__((address_space(3))) void*)(dst0 + m * 1024), 16, 0, 0);
    }
  };

  int pcol[MFR];
#pragma unroll
  for (int mf = 0; mf < MFR; ++mf) pcol[mf] = wv * (MFR * 16) + mf * 16 + ml;

  const bf16x8 bz = {0, 0, 0, 0, 0, 0, 0, 0};
  bf16x8 aCur[MFR][2];
  bf16x8 rN[MFR][NRN];
  float wsv[MFR][4];
  float2 offA[MFR];

  // ---- MODE 0: direct conv A-path ----
  auto issueA0 = [&](int tn) {
    int kk = tn >> 2, chunk = tn & 3;
    int ky = kk / 3, kx = kk - ky * 3;
    int gy = h + ky - 1;
    bool rowok = (gy >= 0) & (gy < 64);
#pragma unroll
    for (int mf = 0; mf < MFR; ++mf) {
      int gx = pcol[mf] + kx - 1;
      bool inb = rowok & (gx >= 0) & (gx < 64);
      const ushort* p =
          inT + ((((size_t)(b * 4 + chunk) << 12) + gy * 64 + gx) << 6) + kc * 8;
      rN[mf][0] = bz;
      rN[mf][1] = bz;
      if (inb) {
        rN[mf][0] = *(const bf16x8*)p;
        rN[mf][1] = *(const bf16x8*)(p + 32);
      }
    }
  };
  auto finishA0 = [&]() {
#pragma unroll
    for (int mf = 0; mf < MFR; ++mf) {
      aCur[mf][0] = rN[mf][0];
      aCur[mf][1] = rN[mf][1];
    }
  };

  // ---- MODE 1: deform A-path ----
  auto loadOff = [&](int tn) {
    int g = tn / 9, kk = tn - 9 * (tn / 9);
    int ch = g * 18 + kk * 2;
#pragma unroll
    for (int mf = 0; mf < MFR; ++mf) {
      const float* offp =
          off + (((size_t)b * 72 + ch) << 12) + h * 64 + pcol[mf];
      offA[mf].x = offp[0];
      offA[mf].y = offp[4096];
    }
  };
  auto issueA1 = [&](int tn) {
    int g = tn / 9, kk = tn - 9 * (tn / 9);
    int ky = kk / 3, kx = kk - ky * 3;
    const ushort* base = inT + (((size_t)(b * 4 + g)) << 18) + kc * 8;
#pragma unroll
    for (int mf = 0; mf < MFR; ++mf) {
      float py = (float)(h + ky - 1) + offA[mf].x;
      float pxf = (float)(pcol[mf] + kx - 1) + offA[mf].y;
      float y0f = floorf(py), x0f = floorf(pxf);
      float wy1 = py - y0f, wx1 = pxf - x0f;
      float wy0 = 1.f - wy1, wx0 = 1.f - wx1;
      int y0 = (int)y0f, x0i = (int)x0f;
      int y1 = y0 + 1, x1i = x0i + 1;
      bool vy0 = (y0 >= 0) & (y0 < 64);
      bool vy1 = (y1 >= 0) & (y1 < 64);
      bool vx0 = (x0i >= 0) & (x0i < 64);
      bool vx1 = (x1i >= 0) & (x1i < 64);
      wsv[mf][0] = (vy0 & vx0) ? wy0 * wx0 : 0.f;
      wsv[mf][1] = (vy0 & vx1) ? wy0 * wx1 : 0.f;
      wsv[mf][2] = (vy1 & vx0) ? wy1 * wx0 : 0.f;
      wsv[mf][3] = (vy1 & vx1) ? wy1 * wx1 : 0.f;
      int yc0 = min(max(y0, 0), 63), yc1 = min(max(y1, 0), 63);
      int xc0 = min(max(x0i, 0), 63), xc1 = min(max(x1i, 0), 63);
      const ushort* p00 = base + ((yc0 * 64 + xc0) << 6);
      const ushort* p01 = base + ((yc0 * 64 + xc1) << 6);
      const ushort* p10 = base + ((yc1 * 64 + xc0) << 6);
      const ushort* p11 = base + ((yc1 * 64 + xc1) << 6);
      rN[mf][0] = *(const bf16x8*)p00;
      rN[mf][1] = *(const bf16x8*)(p00 + 32);
      rN[mf][2] = *(const bf16x8*)p01;
      rN[mf][3] = *(const bf16x8*)(p01 + 32);
      rN[mf][4] = *(const bf16x8*)p10;
      rN[mf][5] = *(const bf16x8*)(p10 + 32);
      rN[mf][6] = *(const bf16x8*)p11;
      rN[mf][7] = *(const bf16x8*)(p11 + 32);
    }
  };
  auto finishA1 = [&]() {
#pragma unroll
    for (int mf = 0; mf < MFR; ++mf) {
      float w00 = wsv[mf][0], w01 = wsv[mf][1];
      float w10 = wsv[mf][2], w11 = wsv[mf][3];
#pragma unroll
      for (int ks = 0; ks < 2; ++ks) {
        bf16x8 q00 = rN[mf][0 + ks], q01 = rN[mf][2 + ks];
        bf16x8 q10 = rN[mf][4 + ks], q11 = rN[mf][6 + ks];
        bf16x8 av;
#pragma unroll
        for (int jj = 0; jj < 4; ++jj) {
          float v0 = w00 * bf2f((ushort)q00[2 * jj]) + w01 * bf2f((ushort)q01[2 * jj]) +
                     w10 * bf2f((ushort)q10[2 * jj]) + w11 * bf2f((ushort)q11[2 * jj]);
          float v1 = w00 * bf2f((ushort)q00[2 * jj + 1]) + w01 * bf2f((ushort)q01[2 * jj + 1]) +
                     w10 * bf2f((ushort)q10[2 * jj + 1]) + w11 * bf2f((ushort)q11[2 * jj + 1]);
          av[2 * jj] = (short)f2bf(v0);
          av[2 * jj + 1] = (short)f2bf(v1);
        }
        aCur[mf][ks] = av;
      }
    }
  };

  f32x4 acc[MFR][NFR];
#pragma unroll
  for (int i = 0; i < MFR; ++i)
#pragma unroll
    for (int j = 0; j < NFR; ++j) acc[i][j] = (f32x4){0.f, 0.f, 0.f, 0.f};

  // prologue
  if (MODE == 1) {
    loadOff(0);
    issueA1(0);
    loadOff(1);
    finishA1();
  } else {
    issueA0(0);
    finishA0();
  }
  stage(0, 0);
  __syncthreads();

  for (int ti = 0; ti < 36; ++ti) {
    int cur = ti & 1;
    if (ti < 35) {
      stage(ti + 1, cur ^ 1);
      if (MODE == 1) issueA1(ti + 1); else issueA0(ti + 1);
    }
    if (MODE == 1 && ti < 34) loadOff(ti + 2);

#pragma unroll
    for (int ks = 0; ks < 2; ++ks) {
      int sw = (((ks * 4 + kc) ^ ml7) << 3);     // swizzled 16B slot
      bf16x8 bq[NFR];
#pragma unroll
      for (int nf = 0; nf < NFR; ++nf)
        bq[nf] = *(const bf16x8*)&Blds[cur][(nf * 16 + ml) * 64 + sw];
#pragma unroll
      for (int mf = 0; mf < MFR; ++mf)
#pragma unroll
        for (int nf = 0; nf < NFR; ++nf)
          acc[mf][nf] = __builtin_amdgcn_mfma_f32_16x16x32_bf16(
              aCur[mf][ks], bq[nf], acc[mf][nf], 0, 0, 0);
    }

    if (ti < 35) { if (MODE == 1) finishA1(); else finishA0(); }
    __syncthreads();
  }

  // epilogue: D col = lane&15 (co), row = (lane>>4)*4 + ri (px)
  int rq = lane >> 4;
#pragma unroll
  for (int nf = 0; nf < NFR; ++nf) {
    int cog = nf * 16 + ml;
    if (cog < co_write) {
      float bv = HASBIAS ? bias[cog] : 0.f;
#pragma unroll
      for (int mf = 0; mf < MFR; ++mf) {
#pragma unroll
        for (int ri = 0; ri < 4; ++ri) {
          int pxe = wv * (MFR * 16) + mf * 16 + rq * 4 + ri;
          float v = acc[mf][nf][ri] + bv;
          if (RELU) v = fmaxf(v, 0.f);
          if (OUT_CHLAST) {
            int g_out = cog >> 6, ci = cog & 63;
            ((ushort*)outp)[((((size_t)(b * 4 + g_out) << 12) + h * 64 + pxe) << 6) + ci] =
                f2bf(v);
          } else {
            ((float*)outp)[(((size_t)b * co_total + cog) << 12) + h * 64 + pxe] = v;
          }
        }
      }
    }
  }
}

extern "C" void kernel_launch(void* const* d_in, const int* in_sizes, int n_in,
                              void* d_out, int out_size, void* d_ws, size_t ws_size,
                              hipStream_t stream) {
  const float* x  = (const float*)d_in[0];
  const float* w1 = (const float*)d_in[1];
  const float* b1 = (const float*)d_in[2];
  const float* w2 = (const float*)d_in[3];
  const float* b2 = (const float*)d_in[4];
  const float* wd = (const float*)d_in[5];

  char* wsb = (char*)d_ws;
  float*  off_buf = (float*)wsb;                  //  9,437,184 B
  ushort* xt      = (ushort*)(wsb + 9437184);     // 16,777,216 B
  ushort* wt1s    = (ushort*)(wsb + 26214400);    //  1,179,648 B (36*256*64)
  ushort* wt2s    = (ushort*)(wsb + 27394048);    //    368,640 B (36*80*64)
  ushort* wtds    = (ushort*)(wsb + 27762688);    //  1,179,648 B -> 28.9 MB

  prep_weights<<<2048, 256, 0, stream>>>(w1, w2, wd, wt1s, wt2s, wtds);
  transpose_x<<<2048, 256, 0, stream>>>(x, xt);

  // conv1: xt -> t1t (bf16 channel-last in d_out); CO_TILE=256, LDS 64KB
  fa_mfma4<0, 2, 16, false, true, true>
      <<<512, 128, 0, stream>>>(xt, nullptr, (const char*)wt1s, b1, d_out, 256, 256);

  // conv2: t1t -> offsets (f32); CO_TILE=80, LDS 20KB (high occupancy)
  fa_mfma4<0, 2, 5, false, true, false>
      <<<512, 128, 0, stream>>>((const ushort*)d_out, nullptr, (const char*)wt2s,
                                b2, off_buf, 72, 72);

  // deform + relu: xt, offsets -> d_out (f32)
  fa_mfma4<1, 2, 16, true, false, false>
      <<<512, 128, 0, stream>>>(xt, off_buf, (const char*)wtds, nullptr, d_out,
                                256, 256);
}